// Round 2
// baseline (662.403 us; speedup 1.0000x reference)
//
#include <hip/hip_runtime.h>
#include <stdint.h>

#define NB  64
#define SEQ 2048
#define DIM 512
#define NS  (NB*SEQ)   // 131072 flattened s-rows

typedef __bf16 bf16x8 __attribute__((ext_vector_type(8)));
typedef float  f32x4  __attribute__((ext_vector_type(4)));
typedef unsigned int u32;
typedef unsigned int u32x4 __attribute__((ext_vector_type(4)));

// pack two fp32 -> two bf16 (round-half-up; bias 2^-24, negligible vs threshold)
__device__ __forceinline__ u32 pk_bf16(float a, float b){
  union {float f; u32 i;} x, y; x.f = a; y.f = b;
  return ((x.i + 0x8000u) >> 16) | ((y.i + 0x8000u) & 0xffff0000u);
}
// tanh(x) = 1 - 2/(e^{2x}+1); saturates correctly at both ends.
__device__ __forceinline__ float fast_tanh(float x){
  float e = __builtin_amdgcn_exp2f(x * 2.885390081777927f);  // 2*log2(e)
  return 1.0f - 2.0f*__builtin_amdgcn_rcpf(e + 1.0f);
}

// ---------------- kernel 1: q = query @ Wq_w^T + Wq_b  (fp32 into ws) -------
__global__ void q_kernel(const float* __restrict__ query, const float* __restrict__ Wq_w,
                         const float* __restrict__ Wq_b, float* __restrict__ qws)
{
  __shared__ float lq[DIM];
  const int b   = blockIdx.x;
  const int tid = threadIdx.x;           // 256
  const int e   = blockIdx.y*256 + tid;  // 0..511
  for (int i = tid; i < DIM; i += 256) lq[i] = query[b*DIM + i];
  __syncthreads();
  const float* wr = Wq_w + (size_t)e*DIM;
  float acc = 0.f;
  for (int d = 0; d < DIM; d += 4){
    f32x4 w = *(const f32x4*)(wr + d);
    acc += w.x*lq[d] + w.y*lq[d+1] + w.z*lq[d+2] + w.w*lq[d+3];
  }
  qws[b*DIM + e] = acc + Wq_b[e];
}

// ---------------- kernel 2: main GEMM C[e][s] = Wr_w @ ref^T + fused epilogue
// Tile BM=128(e) x BN=128(s) x BK=32. 256 threads = 4 waves in 2x2.
// fp32 global -> bf16 LDS staging (pack in regs), 16x16x32 bf16 MFMA, 4x4 frags/wave.
#define BM 128
#define BN 128
#define BK 32

__global__ __launch_bounds__(256)
void main_kernel(const float* __restrict__ ref,  const float* __restrict__ Wr_w,
                 const float* __restrict__ Wr_b, const float* __restrict__ value,
                 const float* __restrict__ qws,  float* __restrict__ part,
                 float* __restrict__ out)
{
  // phase1: A bf16 tile [0,8192), B bf16 tile [8192,16384)
  // phase2: ct float[64][132] at [0,33792), lred float[256] at [33792,34816)
  __shared__ __align__(16) char smem[34816];
  char* Al = smem;
  char* Bl = smem + 8192;

  const int tid  = threadIdx.x;
  const int lane = tid & 63, wave = tid >> 6;
  const int wm   = wave >> 1, wn = wave & 1;
  const int col  = lane & 15, quad = lane >> 4;
  const int st   = blockIdx.x;            // s-tile 0..1023
  const int et   = blockIdx.y;            // e-tile 0..3
  const size_t s0 = (size_t)st * BN;
  const int e0   = et * BM;

  // staging role: thread t loads 16 contiguous fp32 of one tile-row half
  const int srow = tid >> 1, half = tid & 1;

  f32x4 acc[4][4];
#pragma unroll
  for (int i = 0; i < 4; ++i)
#pragma unroll
    for (int j = 0; j < 4; ++j) acc[i][j] = (f32x4)0.0f;

  for (int kt = 0; kt < DIM/BK; ++kt){
    const float* ga = Wr_w + (size_t)(e0+srow)*DIM + kt*BK + half*16;
    const float* gb = ref  + (s0+srow)*DIM + (size_t)kt*BK + half*16;
    f32x4 a0 = *(const f32x4*)(ga+0), a1 = *(const f32x4*)(ga+4),
          a2 = *(const f32x4*)(ga+8), a3 = *(const f32x4*)(ga+12);
    f32x4 b0 = *(const f32x4*)(gb+0), b1 = *(const f32x4*)(gb+4),
          b2 = *(const f32x4*)(gb+8), b3 = *(const f32x4*)(gb+12);

    u32x4 pa0, pa1, pb0, pb1;
    pa0[0]=pk_bf16(a0.x,a0.y); pa0[1]=pk_bf16(a0.z,a0.w);
    pa0[2]=pk_bf16(a1.x,a1.y); pa0[3]=pk_bf16(a1.z,a1.w);
    pa1[0]=pk_bf16(a2.x,a2.y); pa1[1]=pk_bf16(a2.z,a2.w);
    pa1[2]=pk_bf16(a3.x,a3.y); pa1[3]=pk_bf16(a3.z,a3.w);
    pb0[0]=pk_bf16(b0.x,b0.y); pb0[1]=pk_bf16(b0.z,b0.w);
    pb0[2]=pk_bf16(b1.x,b1.y); pb0[3]=pk_bf16(b1.z,b1.w);
    pb1[0]=pk_bf16(b2.x,b2.y); pb1[1]=pk_bf16(b2.z,b2.w);
    pb1[2]=pk_bf16(b3.x,b3.y); pb1[3]=pk_bf16(b3.z,b3.w);

    __syncthreads();                      // prev iter's LDS reads done
    {
      const int off = srow*64 + half*32;  // 64 B per bf16 tile-row
      *(u32x4*)(Al + off)      = pa0;
      *(u32x4*)(Al + off + 16) = pa1;
      *(u32x4*)(Bl + off)      = pb0;
      *(u32x4*)(Bl + off + 16) = pb1;
    }
    __syncthreads();                      // staging visible

    bf16x8 af[4], bfr[4];
#pragma unroll
    for (int mi = 0; mi < 4; ++mi){
      const int r = wm*64 + mi*16 + col;  // A row (e); k-offset quad*8
      af[mi] = *(const bf16x8*)(Al + r*64 + quad*16);
    }
#pragma unroll
    for (int ni = 0; ni < 4; ++ni){
      const int r = wn*64 + ni*16 + col;  // B row (s)
      bfr[ni] = *(const bf16x8*)(Bl + r*64 + quad*16);
    }
#pragma unroll
    for (int mi = 0; mi < 4; ++mi)
#pragma unroll
      for (int ni = 0; ni < 4; ++ni)
        acc[mi][ni] = __builtin_amdgcn_mfma_f32_16x16x32_bf16(af[mi], bfr[ni], acc[mi][ni], 0, 0, 0);
  }

  __syncthreads();                        // done with A/B LDS; reuse for transpose
  float* ct   = (float*)smem;             // [64][132] fp32, +4 pad
  float* lred = (float*)(smem + 33792);   // [2][128]

  const int b  = (int)(s0 >> 11);         // s-tile lies within one batch (2048%128==0)
  const int sb = (int)(s0 & 2047);

  float lsum[4] = {0.f, 0.f, 0.f, 0.f};
#pragma unroll
  for (int pass = 0; pass < 2; ++pass){
    if (pass) __syncthreads();            // copy-out of pass 0 done before overwrite
    if (wm == pass){
#pragma unroll
      for (int mi = 0; mi < 4; ++mi){
#pragma unroll
        for (int rg = 0; rg < 4; ++rg){
          const int el = mi*16 + quad*4 + rg;     // C row within 64-row half
          const int eg = e0 + pass*64 + el;
          const float bias = Wr_b[eg];
          const float qe   = qws[b*DIM + eg];
          const float val  = value[eg];
#pragma unroll
          for (int ni = 0; ni < 4; ++ni){
            const int sl = wn*64 + ni*16 + col;   // C col = s (lane&15)
            const float r = acc[mi][ni][rg] + bias;
            ct[el*132 + sl] = r;
            lsum[ni] += fast_tanh(qe + r) * val;
          }
        }
      }
    }
    __syncthreads();
    // coalesced transposed write: 64 rows x 128 floats, float4 stores
#pragma unroll
    for (int it = 0; it < 8; ++it){
      const int c  = it*256 + tid;        // 2048 float4 chunks
      const int rw = c >> 5, ch = c & 31;
      f32x4 v = *(const f32x4*)(ct + rw*132 + ch*4);
      *(f32x4*)(out + ((size_t)(b*DIM + e0 + pass*64 + rw))*SEQ + sb + ch*4) = v;
    }
  }

  // reduce logits partials over the 4 quads (same s, different e chunks)
#pragma unroll
  for (int ni = 0; ni < 4; ++ni){
    lsum[ni] += __shfl_xor(lsum[ni], 16);
    lsum[ni] += __shfl_xor(lsum[ni], 32);
  }
  if (quad == 0){
#pragma unroll
    for (int ni = 0; ni < 4; ++ni)
      lred[wm*128 + wn*64 + ni*16 + col] = lsum[ni];
  }
  __syncthreads();

  if (tid < 128)                          // unique (et, s) slot -> no atomics
    part[(size_t)et*NS + s0 + tid] = lred[tid] + lred[128 + tid];
}

// ---------------- kernel 3: logits = 10*tanh(sum of 4 partials) -------------
__global__ void logits_kernel(const float* __restrict__ part, float* __restrict__ out)
{
  const int i = blockIdx.x*256 + threadIdx.x;   // 131072
  const float s = part[i] + part[NS + i] + part[2*NS + i] + part[3*NS + i];
  out[i] = 10.0f * fast_tanh(s);
}

extern "C" void kernel_launch(void* const* d_in, const int* in_sizes, int n_in,
                              void* d_out, int out_size, void* d_ws, size_t ws_size,
                              hipStream_t stream)
{
  const float* query = (const float*)d_in[0];
  const float* ref   = (const float*)d_in[1];
  const float* Wq_w  = (const float*)d_in[2];
  const float* Wq_b  = (const float*)d_in[3];
  const float* Wr_w  = (const float*)d_in[4];
  const float* Wr_b  = (const float*)d_in[5];
  const float* value = (const float*)d_in[6];
  float* out = (float*)d_out;

  float* qws  = (float*)d_ws;               // 64*512 fp32 = 128 KB
  float* part = (float*)d_ws + NB*DIM;      // 4*131072 fp32 = 2 MB

  q_kernel<<<dim3(NB, 2), dim3(256), 0, stream>>>(query, Wq_w, Wq_b, qws);
  main_kernel<<<dim3(NS/BN, DIM/BM), dim3(256), 0, stream>>>(ref, Wr_w, Wr_b, value,
                                                             qws, part, out);
  logits_kernel<<<dim3(NS/256), dim3(256), 0, stream>>>(part, out + (size_t)NB*DIM*SEQ);
}